// Round 2
// baseline (351.903 us; speedup 1.0000x reference)
//
#include <hip/hip_runtime.h>

// SimpleEncoder R7: LSTM(B=4096,S=512,I=3,H=16) + Linear(16->5) + clip(+-10)
//
// R6 (MFMA gates, LDS scatter/gather) regressed to 256us: two serial LDS
// round-trips per step (hbuf h-feedback, zbuf z-spread) + 15.5M bank
// conflicts = ~600 cyc/step exposed latency at 1 wave/SIMD.
//
// R7 keeps the MFMA math (bit-identical 3-term bf16x2 compensated chains)
// but removes ALL LDS from the recurrence path:
//  - B columns replicated 4x (col&3 = batch). D-layout (row=4q+reg, col)
//    then gives every lane exactly one (unit,batch): unit=4q+(col>>2),
//    batch=col&3. Activations (10 trans) run 64-wide straight out of the
//    MFMA destination regs (static-index cndmask select, no LDS).
//  - h feedback: each lane packs its h to one {bf16hi|bf16lo} dword; the
//    8 B-fragment slots are gathered by 8 ds_bpermute off ONE uniform src
//    reg with precomputed per-lane addresses (one DS latency, no banks).
//  - x slots (k=16..18, q==2 lanes): xs staging now stores PRE-PACKED
//    hi/lo dwords; one prefetchable ds_read_b128/step, zero per-step pack.
// Lin head (W_lin.h) reuses the same B-fragment, 3 MFMAs, off-critical.
// Grid/occupancy unchanged: 256 blocks x 256 thr = 1024 waves = 1/SIMD.

#define TS 512
#define LOG2E 1.44269504088896340736f

typedef float f32x4 __attribute__((ext_vector_type(4)));
typedef short s16x8 __attribute__((ext_vector_type(8)));
typedef unsigned int u32;
typedef u32 u32x4 __attribute__((ext_vector_type(4)));
typedef f32x4 f32x4u __attribute__((aligned(4)));   // out rows are only 4B-aligned

static __device__ __forceinline__ float clip10(float v) {
  return fminf(fmaxf(v, -10.0f), 10.0f);
}
// pack f32 -> {bf16(hi) | bf16(v-hi)} in one dword (truncation split)
static __device__ __forceinline__ u32 packhl(float v) {
  const u32 vb = __float_as_uint(v);
  const float hif = __uint_as_float(vb & 0xFFFF0000u);
  const float lof = v - hif;
  return __builtin_amdgcn_perm(vb, __float_as_uint(lof), 0x07060302u);
}

__global__ __launch_bounds__(256)
__attribute__((amdgpu_waves_per_eu(1, 1)))
void lstm_enc_kernel(const float* __restrict__ x,
                     const float* __restrict__ W_ih,
                     const float* __restrict__ W_hh,
                     const float* __restrict__ b_ih,
                     const float* __restrict__ b_hh,
                     const float* __restrict__ W_lin,
                     const float* __restrict__ b_lin,
                     float* __restrict__ out) {
  const int tid = threadIdx.x;
  const int w   = tid >> 6;         // wave in block (0..3)
  const int q   = (tid >> 4) & 3;   // quad within wave (MFMA row-group / B k-group)
  const int col = tid & 15;         // MFMA col; batch = col&3, replica = col>>2
  const int b   = col & 3;
  const int rep = col >> 2;
  const int g16 = tid >> 4;         // staging group (batch slot in block)

  // x staging: pre-packed hi/lo dwords, [parity][step-in-chunk][batch-slot]
  __shared__ u32x4 xs[2][64][16];
  u32x4* xsf = &xs[0][0][0];

  // ---- A-fragments (once). Logical k = q*8 + e, same convention on A & B.
  // k<16: W_hh[gate row][k]; k=16..18: W_ih[gate row][k-16]; else 0. LOG2E
  // folded (2x for g-gate). Truncation split: v = hi + lo.
  s16x8 a_hi[4], a_lo[4];
#pragma unroll
  for (int G = 0; G < 4; ++G) {
    const float sc = (G == 2) ? (2.0f * LOG2E) : LOG2E;
#pragma unroll
    for (int e = 0; e < 8; ++e) {
      const int k = q * 8 + e;
      float v = 0.0f;
      if (k < 16)      v = W_hh[(G * 16 + col) * 16 + k] * sc;
      else if (k < 19) v = W_ih[(G * 16 + col) * 3 + (k - 16)] * sc;
      const u32 vb = __float_as_uint(v);
      const float hif = __uint_as_float(vb & 0xFFFF0000u);
      const float lof = v - hif;
      a_hi[G][e] = (short)(vb >> 16);
      a_lo[G][e] = (short)(__float_as_uint(lof) >> 16);
    }
  }
  s16x8 l_hi, l_lo;
#pragma unroll
  for (int e = 0; e < 8; ++e) {
    const int k = q * 8 + e;
    const float v = (col < 5 && k < 16) ? W_lin[col * 16 + k] : 0.0f;
    const u32 vb = __float_as_uint(v);
    const float hif = __uint_as_float(vb & 0xFFFF0000u);
    const float lof = v - hif;
    l_hi[e] = (short)(vb >> 16);
    l_lo[e] = (short)(__float_as_uint(lof) >> 16);
  }
  // C-init biases: D row = 4q + reg.
  f32x4 bias_c[4];
#pragma unroll
  for (int G = 0; G < 4; ++G) {
    const float sc = (G == 2) ? (2.0f * LOG2E) : LOG2E;
#pragma unroll
    for (int r = 0; r < 4; ++r)
      bias_c[G][r] = (b_ih[G * 16 + q * 4 + r] + b_hh[G * 16 + q * 4 + r]) * sc;
  }
  f32x4 blin_c;
#pragma unroll
  for (int r = 0; r < 4; ++r) {
    const int row = q * 4 + r;
    blin_c[r] = (row < 5) ? b_lin[row] : 0.0f;
  }

  // ---- bpermute addresses: consumer lane (q,col) element e wants
  // h[u = (q&1)*8+e][batch b], produced by lane 16*(u>>2)+4*(u&3)+b.
  // (only meaningful for q<2; q>=2 slots come from x / zero.)
  int bpa[8];
#pragma unroll
  for (int e = 0; e < 8; ++e) {
    const int u = (q & 1) * 8 + e;
    bpa[e] = (16 * (u >> 2) + 4 * (u & 3) + b) * 4;
  }
  const bool is_h = (q < 2);
  const bool is_x = (q == 2);
  const bool r1 = (rep & 1) != 0;
  const bool r2 = (rep & 2) != 0;

  // ---- x staging (R5/R6 scheme, but values stored PRE-PACKED hi/lo)
  const int batch_g = blockIdx.x * 16 + g16;
  const float* __restrict__ xb = x + (size_t)batch_g * (TS * 3);
  const float* xc0 = xb + col * 12;             // lane owns steps 4col..4col+3
  float4 p0, p1, p2;
  p0 = *(const float4*)(xc0 + 0);
  p1 = *(const float4*)(xc0 + 4);
  p2 = *(const float4*)(xc0 + 8);
  {
    const int wb = col * 64 + g16;
    xsf[wb +  0] = u32x4{packhl(p0.x), packhl(p0.y), packhl(p0.z), 0u};
    xsf[wb + 16] = u32x4{packhl(p0.w), packhl(p1.x), packhl(p1.y), 0u};
    xsf[wb + 32] = u32x4{packhl(p1.z), packhl(p1.w), packhl(p2.x), 0u};
    xsf[wb + 48] = u32x4{packhl(p2.y), packhl(p2.z), packhl(p2.w), 0u};
  }
  p0 = *(const float4*)(xc0 + 192 + 0);
  p1 = *(const float4*)(xc0 + 192 + 4);
  p2 = *(const float4*)(xc0 + 192 + 8);

  float* __restrict__ ob = out + (size_t)(blockIdx.x * 16 + w * 4 + b) * (TS * 5);
  const int xri = w * 4 + b;                    // x read slot (this wave's batch b)

  float h = 0.0f, c = 0.0f;

  auto step = [&](int s) {
    // x for THIS step (independent of h; latency hides under bpermute wait)
    const u32x4 xq = xsf[((s & 127) << 4) + xri];

    // pack h_{s-1} and gather the B-fragment via 8 bpermutes (one DS latency)
    const u32 hpk = packhl(h);
    u32 bp[8];
#pragma unroll
    for (int e = 0; e < 8; ++e)
      bp[e] = (u32)__builtin_amdgcn_ds_bpermute(bpa[e], (int)hpk);

    // assemble packed B slots: q<2 -> h, q==2 -> x (e<3; e==3 pad is 0), q==3 -> 0
    u32 pk0 = is_h ? bp[0] : (is_x ? xq.x : 0u);
    u32 pk1 = is_h ? bp[1] : (is_x ? xq.y : 0u);
    u32 pk2 = is_h ? bp[2] : (is_x ? xq.z : 0u);
    u32 pk3 = is_h ? bp[3] : 0u;
    u32 pk4 = is_h ? bp[4] : 0u;
    u32 pk5 = is_h ? bp[5] : 0u;
    u32 pk6 = is_h ? bp[6] : 0u;
    u32 pk7 = is_h ? bp[7] : 0u;

    // split packed dwords -> {hi,lo} bf16 fragments (8 v_perm)
    u32x4 hi4, lo4;
    hi4.x = __builtin_amdgcn_perm(pk1, pk0, 0x07060302u);
    lo4.x = __builtin_amdgcn_perm(pk1, pk0, 0x05040100u);
    hi4.y = __builtin_amdgcn_perm(pk3, pk2, 0x07060302u);
    lo4.y = __builtin_amdgcn_perm(pk3, pk2, 0x05040100u);
    hi4.z = __builtin_amdgcn_perm(pk5, pk4, 0x07060302u);
    lo4.z = __builtin_amdgcn_perm(pk5, pk4, 0x05040100u);
    hi4.w = __builtin_amdgcn_perm(pk7, pk6, 0x07060302u);
    lo4.w = __builtin_amdgcn_perm(pk7, pk6, 0x05040100u);
    const s16x8 Bhi = __builtin_bit_cast(s16x8, hi4);
    const s16x8 Blo = __builtin_bit_cast(s16x8, lo4);

    // gates: z_G = Wlo*Bhi + Whi*Blo + Whi*Bhi + bias (bit-identical to R6)
    f32x4 z0 = __builtin_amdgcn_mfma_f32_16x16x32_bf16(a_lo[0], Bhi, bias_c[0], 0, 0, 0);
    f32x4 z1 = __builtin_amdgcn_mfma_f32_16x16x32_bf16(a_lo[1], Bhi, bias_c[1], 0, 0, 0);
    f32x4 z2 = __builtin_amdgcn_mfma_f32_16x16x32_bf16(a_lo[2], Bhi, bias_c[2], 0, 0, 0);
    f32x4 z3 = __builtin_amdgcn_mfma_f32_16x16x32_bf16(a_lo[3], Bhi, bias_c[3], 0, 0, 0);
    f32x4 ov = __builtin_amdgcn_mfma_f32_16x16x32_bf16(l_lo,    Bhi, blin_c,    0, 0, 0);
    z0 = __builtin_amdgcn_mfma_f32_16x16x32_bf16(a_hi[0], Blo, z0, 0, 0, 0);
    z1 = __builtin_amdgcn_mfma_f32_16x16x32_bf16(a_hi[1], Blo, z1, 0, 0, 0);
    z2 = __builtin_amdgcn_mfma_f32_16x16x32_bf16(a_hi[2], Blo, z2, 0, 0, 0);
    z3 = __builtin_amdgcn_mfma_f32_16x16x32_bf16(a_hi[3], Blo, z3, 0, 0, 0);
    ov = __builtin_amdgcn_mfma_f32_16x16x32_bf16(l_hi,    Blo, ov, 0, 0, 0);
    z0 = __builtin_amdgcn_mfma_f32_16x16x32_bf16(a_hi[0], Bhi, z0, 0, 0, 0);
    z1 = __builtin_amdgcn_mfma_f32_16x16x32_bf16(a_hi[1], Bhi, z1, 0, 0, 0);
    z2 = __builtin_amdgcn_mfma_f32_16x16x32_bf16(a_hi[2], Bhi, z2, 0, 0, 0);
    z3 = __builtin_amdgcn_mfma_f32_16x16x32_bf16(a_hi[3], Bhi, z3, 0, 0, 0);
    ov = __builtin_amdgcn_mfma_f32_16x16x32_bf16(l_hi,    Bhi, ov, 0, 0, 0);

    // linear head (W_lin . h_{s-1} -> out[s-1]); replica 0 lanes store
    if (s > 0 && col < 4) {
      if (q == 0) {
        f32x4 o;
        o.x = clip10(ov.x); o.y = clip10(ov.y); o.z = clip10(ov.z); o.w = clip10(ov.w);
        *(f32x4u*)(ob + (s - 1) * 5) = o;
      } else if (q == 1) {
        ob[(s - 1) * 5 + 4] = clip10(ov.x);
      }
    }

    // this lane's unit = 4q + rep: static-index select element `rep` (cndmask)
    const float zi  = r2 ? (r1 ? z0[3] : z0[2]) : (r1 ? z0[1] : z0[0]);
    const float zfg = r2 ? (r1 ? z1[3] : z1[2]) : (r1 ? z1[1] : z1[0]);
    const float zg  = r2 ? (r1 ? z2[3] : z2[2]) : (r1 ? z2[1] : z2[0]);
    const float zo  = r2 ? (r1 ? z3[3] : z3[2]) : (r1 ? z3[1] : z3[0]);

    // activations (identical math to R5/R6; log2e pre-folded)
    const float ig = __builtin_amdgcn_rcpf(1.0f + __builtin_amdgcn_exp2f(-zi));
    const float fg = __builtin_amdgcn_rcpf(1.0f + __builtin_amdgcn_exp2f(-zfg));
    const float sg = __builtin_amdgcn_rcpf(1.0f + __builtin_amdgcn_exp2f(zg));
    const float og = __builtin_amdgcn_rcpf(1.0f + __builtin_amdgcn_exp2f(-zo));
    const float gg = fmaf(-2.0f, sg, 1.0f);
    c = fmaf(fg, c, ig * gg);
    const float tc = fmaf(-2.0f,
        __builtin_amdgcn_rcpf(1.0f + __builtin_amdgcn_exp2f((2.0f * LOG2E) * c)), 1.0f);
    h = og * tc;
  };

  for (int ch = 0; ch < 8; ++ch) {
    const int base = ch * 64;
#pragma unroll 2
    for (int u = 0; u < 32; ++u) step(base + u);

    // mid-chunk: stage chunk ch+1 (regs loaded ~64 steps ago), start ch+2 loads
    if (ch < 7) {
      const int p = (ch + 1) & 1;
      const int wb = p * 1024 + col * 64 + g16;
      xsf[wb +  0] = u32x4{packhl(p0.x), packhl(p0.y), packhl(p0.z), 0u};
      xsf[wb + 16] = u32x4{packhl(p0.w), packhl(p1.x), packhl(p1.y), 0u};
      xsf[wb + 32] = u32x4{packhl(p1.z), packhl(p1.w), packhl(p2.x), 0u};
      xsf[wb + 48] = u32x4{packhl(p2.y), packhl(p2.z), packhl(p2.w), 0u};
    }
    if (ch < 6) {
      const float* xc = xc0 + (ch + 2) * 192;
      p0 = *(const float4*)(xc + 0);
      p1 = *(const float4*)(xc + 4);
      p2 = *(const float4*)(xc + 8);
    }

#pragma unroll 2
    for (int u = 32; u < 64; ++u) step(base + u);
  }

  // epilogue: out[S-1] from h_{S-1} (x slots irrelevant: l_* zero for k>=16)
  {
    const u32 hpk = packhl(h);
    u32 bp[8];
#pragma unroll
    for (int e = 0; e < 8; ++e)
      bp[e] = (u32)__builtin_amdgcn_ds_bpermute(bpa[e], (int)hpk);
    u32 pk0 = is_h ? bp[0] : 0u;
    u32 pk1 = is_h ? bp[1] : 0u;
    u32 pk2 = is_h ? bp[2] : 0u;
    u32 pk3 = is_h ? bp[3] : 0u;
    u32 pk4 = is_h ? bp[4] : 0u;
    u32 pk5 = is_h ? bp[5] : 0u;
    u32 pk6 = is_h ? bp[6] : 0u;
    u32 pk7 = is_h ? bp[7] : 0u;
    u32x4 hi4, lo4;
    hi4.x = __builtin_amdgcn_perm(pk1, pk0, 0x07060302u);
    lo4.x = __builtin_amdgcn_perm(pk1, pk0, 0x05040100u);
    hi4.y = __builtin_amdgcn_perm(pk3, pk2, 0x07060302u);
    lo4.y = __builtin_amdgcn_perm(pk3, pk2, 0x05040100u);
    hi4.z = __builtin_amdgcn_perm(pk5, pk4, 0x07060302u);
    lo4.z = __builtin_amdgcn_perm(pk5, pk4, 0x05040100u);
    hi4.w = __builtin_amdgcn_perm(pk7, pk6, 0x07060302u);
    lo4.w = __builtin_amdgcn_perm(pk7, pk6, 0x05040100u);
    const s16x8 Bhi = __builtin_bit_cast(s16x8, hi4);
    const s16x8 Blo = __builtin_bit_cast(s16x8, lo4);
    f32x4 ov = __builtin_amdgcn_mfma_f32_16x16x32_bf16(l_lo, Bhi, blin_c, 0, 0, 0);
    ov = __builtin_amdgcn_mfma_f32_16x16x32_bf16(l_hi, Blo, ov, 0, 0, 0);
    ov = __builtin_amdgcn_mfma_f32_16x16x32_bf16(l_hi, Bhi, ov, 0, 0, 0);
    if (col < 4) {
      if (q == 0) {
        f32x4 o;
        o.x = clip10(ov.x); o.y = clip10(ov.y); o.z = clip10(ov.z); o.w = clip10(ov.w);
        *(f32x4u*)(ob + (TS - 1) * 5) = o;
      } else if (q == 1) {
        ob[(TS - 1) * 5 + 4] = clip10(ov.x);
      }
    }
  }
}

extern "C" void kernel_launch(void* const* d_in, const int* in_sizes, int n_in,
                              void* d_out, int out_size, void* d_ws, size_t ws_size,
                              hipStream_t stream) {
  const float* x     = (const float*)d_in[0];
  const float* W_ih  = (const float*)d_in[1];
  const float* W_hh  = (const float*)d_in[2];
  const float* b_ih  = (const float*)d_in[3];
  const float* b_hh  = (const float*)d_in[4];
  const float* W_lin = (const float*)d_in[5];
  const float* b_lin = (const float*)d_in[6];
  float* out = (float*)d_out;

  const int B = in_sizes[0] / (TS * 3);   // 4096
  const int grid = B / 16;                // 16 batch elements per 256-thread block
  lstm_enc_kernel<<<grid, 256, 0, stream>>>(x, W_ih, W_hh, b_ih, b_hh, W_lin, b_lin, out);
}

// Round 3
// 259.990 us; speedup vs baseline: 1.3535x; 1.3535x over previous
//
#include <hip/hip_runtime.h>

// SimpleEncoder R8: LSTM(B=4096,S=512,I=3,H=16) + Linear(16->5) + clip(+-10)
//
// R6/R7 (MFMA forms) regressed: at 1 wave/SIMD the gather latency
// (LDS/bpermute + 16cyc/link dependent MFMA chains) is unhideable and
// exceeds the ~130 issue-cyc the matrix pipe saves. Reverting to R5's
// all-VALU math, and attacking R5's real limit instead: occupancy.
// R5 = 717 cyc/step, 60% busy, ~290 stall, 1 wave/SIMD (1024 waves fixed
// by the 16-lanes/batch mapping) -- nothing to overlap stalls with.
//
// R8: k-split each dot product across 32 lanes/batch -> 2048 waves ->
// 2 waves/SIMD. Lane (u = l&15, hh = l>>4) accumulates gate partials over
// k in [8hh, 8hh+8); per-SIMD MAC issue is conserved, stalls overlap
// across the two resident waves.
//  - h-redistribution: one row_ror:8 DPP + cndmask, then 8 row_newbcast
//    DPPs give row hh its k-half (replaces R5's 16 BCASTs).
//  - cross-half reduce: 5x ds_swizzle xor-16 (0x401F) + adds. Only new
//    latency; hidden by the sibling wave.
//  - acts 2x redundant (bit-exact in both halves: a+b == b+a) -- +80
//    trans-cyc/SIMD/step, the price of 2x occupancy. 4-way split would
//    triple trans; 2-way is the sweet spot.
//  - x terms charged to hh=1 lanes, biases to hh=0 (per-lane weight regs,
//    zero extra instructions).
//  - waves_per_eu(2) (R5's (1,1) would FORBID the second resident wave);
//    ~110 VGPRs fits 2 waves/EU (256 budget) easily.
// Grid: 8 batches/block, 512 blocks x 256 thr = 2048 waves = 2/SIMD.

#define TS 512
#define LOG2E 1.44269504088896340736f

typedef float f32x2 __attribute__((ext_vector_type(2)));

// DPP row_newbcast:K -- broadcast lane K of each 16-lane row to the row.
#define BCAST(K) hbr[K] = __int_as_float( \
    __builtin_amdgcn_update_dpp(0, hvi, 0x150 + (K), 0xf, 0xf, true))
#define BCAST8() \
  BCAST(0); BCAST(1); BCAST(2); BCAST(3); BCAST(4); BCAST(5); BCAST(6); BCAST(7)

// xor-16 lane swap within each 32-lane group (ds_swizzle BitMode 0x401F)
static __device__ __forceinline__ float swz16(float v) {
  return __int_as_float(__builtin_amdgcn_ds_swizzle(__float_as_int(v), 0x401F));
}

__global__ __launch_bounds__(256)
__attribute__((amdgpu_waves_per_eu(2)))
void lstm_enc_kernel(const float* __restrict__ x,
                     const float* __restrict__ W_ih,
                     const float* __restrict__ W_hh,
                     const float* __restrict__ b_ih,
                     const float* __restrict__ b_hh,
                     const float* __restrict__ W_lin,
                     const float* __restrict__ b_lin,
                     float* __restrict__ out) {
  const int tid = threadIdx.x;
  const int u   = tid & 15;          // hidden unit
  const int hh  = (tid >> 4) & 1;    // k-half: this lane sums k in [8hh, 8hh+8)
  const int g8  = tid >> 5;          // batch slot within block (0..7)
  const int l32 = tid & 31;          // lane within batch
  const int batch = blockIdx.x * 8 + g8;
  const int jo = (u < 5) ? u : 0;    // clamped row for W_lin loads

  // x staging: xs[parity][step-in-chunk(128)][batch-slot] as float4 (pad 4th)
  __shared__ float4 xs[2][128][8];
  float4* xsf = &xs[0][0][0];        // flat: idx = (s & 255)*8 + g8

  // ---- per-lane weights: this lane's k-half, log2e folded (2x for g-gate)
  f32x2 wif[8], wgo[8];              // {W_i,W_f}[k], {W_g,W_o}[k], k = 8hh+e
  float wl[8];
#pragma unroll
  for (int e = 0; e < 8; ++e) {
    const int k = hh * 8 + e;
    wif[e] = f32x2{W_hh[(u     ) * 16 + k] * LOG2E,
                   W_hh[(u + 16) * 16 + k] * LOG2E};
    wgo[e] = f32x2{W_hh[(u + 32) * 16 + k] * (2.0f * LOG2E),
                   W_hh[(u + 48) * 16 + k] * LOG2E};
    wl[e]  = W_lin[jo * 16 + k];
  }
  // x weights: counted ONCE -> only hh==1 lanes carry them (hh==0 gets 0)
  f32x2 xw[3], xwg[3];
#pragma unroll
  for (int i = 0; i < 3; ++i) {
    if (hh) {
      xw[i]  = f32x2{W_ih[(u     ) * 3 + i] * LOG2E,
                     W_ih[(u + 16) * 3 + i] * LOG2E};
      xwg[i] = f32x2{W_ih[(u + 32) * 3 + i] * (2.0f * LOG2E),
                     W_ih[(u + 48) * 3 + i] * LOG2E};
    } else {
      xw[i] = f32x2{0.f, 0.f};
      xwg[i] = f32x2{0.f, 0.f};
    }
  }
  // biases: counted ONCE -> hh==0 lanes only
  const f32x2 bif = hh ? f32x2{0.f, 0.f}
                       : f32x2{(b_ih[u     ] + b_hh[u     ]) * LOG2E,
                               (b_ih[u + 16] + b_hh[u + 16]) * LOG2E};
  const f32x2 bgo = hh ? f32x2{0.f, 0.f}
                       : f32x2{(b_ih[u + 32] + b_hh[u + 32]) * (2.0f * LOG2E),
                               (b_ih[u + 48] + b_hh[u + 48]) * LOG2E};
  const float bl = hh ? 0.f : b_lin[jo];

  const float* __restrict__ xb = x + (size_t)batch * (TS * 3);
  float* __restrict__ ob = out + (size_t)batch * (TS * 5) + u;
  const bool storer = (u < 5) && (hh == 0);

  // ---- staging: 128-step chunks (384 floats/batch); lane l32 owns steps
  // 4*l32..4*l32+3 of each chunk (12 floats). Intra-wave only (a wave holds
  // batch slots 2w, 2w+1 and stages exactly those) -> no barriers.
  const float* xc0 = xb + l32 * 12;  // + chunk*384 floats
  float4 q0, q1, q2;
  q0 = *(const float4*)(xc0 + 0);
  q1 = *(const float4*)(xc0 + 4);
  q2 = *(const float4*)(xc0 + 8);
  {
    const int wb = (l32 * 4) * 8 + g8;     // parity 0 base
    xsf[wb +  0] = float4{q0.x, q0.y, q0.z, 0.f};
    xsf[wb +  8] = float4{q0.w, q1.x, q1.y, 0.f};
    xsf[wb + 16] = float4{q1.z, q1.w, q2.x, 0.f};
    xsf[wb + 24] = float4{q2.y, q2.z, q2.w, 0.f};
  }
  q0 = *(const float4*)(xc0 + 384 + 0);
  q1 = *(const float4*)(xc0 + 384 + 4);
  q2 = *(const float4*)(xc0 + 384 + 8);

  // prefetch x for steps 0 and 1
  float4 xr[2];
  xr[0] = xsf[0 * 8 + g8];
  xr[1] = xsf[1 * 8 + g8];

  float h = 0.0f, c = 0.0f;

  auto step = [&](int s, int slot) {
    const float4 xt = xr[slot];
    // issue ds_read for step s+2 into the slot just freed
    xr[slot] = xsf[(((s + 2) & 255) << 3) + g8];

    // distribute h_{s-1}: row hh needs h[8hh..8hh+7]. One ror:8 + cndmask
    // makes row_newbcast:K deliver h[K] to row0 and h[K+8] to row1.
    const float h_rot = __int_as_float(
        __builtin_amdgcn_update_dpp(0, __float_as_int(h), 0x128, 0xf, 0xf, true));
    const float hs = hh ? h_rot : h;
    const int hvi = __float_as_int(hs);
    float hbr[8];
    BCAST8();

    // gate partials over this lane's k-half; dual chains for ILP
    f32x2 aa = bif, ab = f32x2{0.f, 0.f};
    f32x2 ga = bgo, gb = f32x2{0.f, 0.f};
    float oa0 = bl, oa1 = 0.f;
    aa = f32x2{xt.x, xt.x} * xw[0] + aa;       // hh==0: xw==0 (bias only)
    ab = f32x2{xt.y, xt.y} * xw[1] + ab;
    aa = f32x2{xt.z, xt.z} * xw[2] + aa;
    ga = f32x2{xt.x, xt.x} * xwg[0] + ga;
    gb = f32x2{xt.y, xt.y} * xwg[1] + gb;
    ga = f32x2{xt.z, xt.z} * xwg[2] + ga;
#pragma unroll
    for (int e = 0; e < 8; e += 2) {
      const f32x2 h0 = f32x2{hbr[e], hbr[e]};
      const f32x2 h1 = f32x2{hbr[e + 1], hbr[e + 1]};
      aa = h0 * wif[e] + aa;
      ab = h1 * wif[e + 1] + ab;
      ga = h0 * wgo[e] + ga;
      gb = h1 * wgo[e + 1] + gb;
      oa0 = fmaf(hbr[e], wl[e], oa0);
      oa1 = fmaf(hbr[e + 1], wl[e + 1], oa1);
    }
    const f32x2 zl = aa + ab;                  // local {i,f} partial
    const f32x2 gl = ga + gb;                  // local {g,o} partial
    const float oal = oa0 + oa1;

    // cross-half reduction: add the xor-16 partner's partials
    const float zi  = zl.x + swz16(zl.x);
    const float zfg = zl.y + swz16(zl.y);
    const float zg  = gl.x + swz16(gl.x);
    const float zo  = gl.y + swz16(gl.y);
    const float oa  = oal + swz16(oal);

    // output projection W_lin . h_{s-1} -> out[s-1]
    if (s > 0 && storer) {
      ob[(s - 1) * 5] = fminf(fmaxf(oa, -10.0f), 10.0f);
    }

    // activations (identical math to R5; log2e pre-folded). Both halves
    // compute identical values (a+b == b+a bit-exact) so h/c stay coherent.
    const float ig = __builtin_amdgcn_rcpf(1.0f + __builtin_amdgcn_exp2f(-zi));
    const float fg = __builtin_amdgcn_rcpf(1.0f + __builtin_amdgcn_exp2f(-zfg));
    const float sg = __builtin_amdgcn_rcpf(1.0f + __builtin_amdgcn_exp2f(zg));
    const float og = __builtin_amdgcn_rcpf(1.0f + __builtin_amdgcn_exp2f(-zo));

    const float gg = fmaf(-2.0f, sg, 1.0f);    // tanh(g)
    c = fmaf(fg, c, ig * gg);
    const float tc = fmaf(-2.0f,
        __builtin_amdgcn_rcpf(1.0f + __builtin_amdgcn_exp2f((2.0f * LOG2E) * c)), 1.0f);
    h = og * tc;
  };

  for (int ch = 0; ch < 4; ++ch) {
    const int base = ch * 128;

    // first half of the chunk
#pragma unroll 2
    for (int v = 0; v < 64; ++v) step(base + v, v & 1);

    // mid-chunk: stage chunk ch+1 (regs loaded ~128 steps ago), start ch+2 loads
    if (ch < 3) {
      const int p = (ch + 1) & 1;
      const int wb = (p * 128 + l32 * 4) * 8 + g8;
      xsf[wb +  0] = float4{q0.x, q0.y, q0.z, 0.f};
      xsf[wb +  8] = float4{q0.w, q1.x, q1.y, 0.f};
      xsf[wb + 16] = float4{q1.z, q1.w, q2.x, 0.f};
      xsf[wb + 24] = float4{q2.y, q2.z, q2.w, 0.f};
    }
    if (ch < 2) {
      const float* xc = xc0 + (ch + 2) * 384;
      q0 = *(const float4*)(xc + 0);
      q1 = *(const float4*)(xc + 4);
      q2 = *(const float4*)(xc + 8);
    }

    // second half of the chunk
#pragma unroll 2
    for (int v = 64; v < 128; ++v) step(base + v, v & 1);
  }

  // final timestep's output (uses h_{S-1})
  {
    const float h_rot = __int_as_float(
        __builtin_amdgcn_update_dpp(0, __float_as_int(h), 0x128, 0xf, 0xf, true));
    const float hs = hh ? h_rot : h;
    const int hvi = __float_as_int(hs);
    float hbr[8];
    BCAST8();
    float oa0 = bl, oa1 = 0.f;
#pragma unroll
    for (int e = 0; e < 8; e += 2) {
      oa0 = fmaf(hbr[e], wl[e], oa0);
      oa1 = fmaf(hbr[e + 1], wl[e + 1], oa1);
    }
    const float oal = oa0 + oa1;
    const float oa = oal + swz16(oal);
    if (storer) {
      ob[(TS - 1) * 5] = fminf(fmaxf(oa, -10.0f), 10.0f);
    }
  }
}

extern "C" void kernel_launch(void* const* d_in, const int* in_sizes, int n_in,
                              void* d_out, int out_size, void* d_ws, size_t ws_size,
                              hipStream_t stream) {
  const float* x     = (const float*)d_in[0];
  const float* W_ih  = (const float*)d_in[1];
  const float* W_hh  = (const float*)d_in[2];
  const float* b_ih  = (const float*)d_in[3];
  const float* b_hh  = (const float*)d_in[4];
  const float* W_lin = (const float*)d_in[5];
  const float* b_lin = (const float*)d_in[6];
  float* out = (float*)d_out;

  const int B = in_sizes[0] / (TS * 3);   // 4096
  const int grid = B / 8;                 // 8 batches per 256-thread block
  lstm_enc_kernel<<<grid, 256, 0, stream>>>(x, W_ih, W_hh, b_ih, b_hh, W_lin, b_lin, out);
}

// Round 4
// 218.560 us; speedup vs baseline: 1.6101x; 1.1896x over previous
//
#include <hip/hip_runtime.h>

// SimpleEncoder R9: LSTM(B=4096,S=512,I=3,H=16) + Linear(16->5) + clip(+-10)
//
// R6-R8 post-mortems: MFMA forms lose (gather+chain latency naked at 1
// wave/SIMD); 2-wave k-split loses (per-wave-step scaffold ~150cyc + trans
// block duplicate per wave; measured 975 vs 717 cyc per 4-batch step).
// R9 = R5's proven structure (16 lanes/batch, DPP broadcast, pk dual-gate
// MACs, LDS x-staging, 1 wave/SIMD) + three local shavings:
//  1. paired reciprocals: sigmoid(i),sigmoid(f) share one rcp via
//     R=rcp((1+Ei)(1+Ef)); ig=(1+Ef)R; fg=(1+Ei)R (exact algebra); same
//     for (g,o). 4 rcp -> 2 rcp + 6 VALU. Trans pipe (~16cyc/wave64-instr,
//     serialized) is the largest single block of R5's 430 busy-cyc.
//  2. scaled-c: carry cs = 2*log2e*c (fold scale into gg2 = 2L - 4L*sg),
//     deleting the mul feeding exp2 in the tanh(c) chain (-1 instr, -4cyc
//     critical-path).
//  3. quad accumulation chains (aa..ad / ga..gd): dependent-FMA depth
//     feeding z halved 8->4 (-14cyc latency) for +6 reduce adds.
// Everything else (layout, staging, waves_per_eu(1,1), store path) = R5.

#define TS 512
#define LOG2E 1.44269504088896340736f

typedef float f32x2 __attribute__((ext_vector_type(2)));

// DPP row_newbcast:K — broadcast lane K of each 16-lane row to the whole row.
#define BCAST(K) hbr[K] = __int_as_float( \
    __builtin_amdgcn_update_dpp(0, hvi, 0x150 + (K), 0xf, 0xf, true))
#define BCAST_ALL() \
  BCAST(0); BCAST(1); BCAST(2); BCAST(3); BCAST(4); BCAST(5); BCAST(6); BCAST(7); \
  BCAST(8); BCAST(9); BCAST(10); BCAST(11); BCAST(12); BCAST(13); BCAST(14); BCAST(15)

__global__ __launch_bounds__(256)
__attribute__((amdgpu_waves_per_eu(1, 1)))
void lstm_enc_kernel(const float* __restrict__ x,
                     const float* __restrict__ W_ih,
                     const float* __restrict__ W_hh,
                     const float* __restrict__ b_ih,
                     const float* __restrict__ b_hh,
                     const float* __restrict__ W_lin,
                     const float* __restrict__ b_lin,
                     float* __restrict__ out) {
  const int tid = threadIdx.x;
  const int j = tid & 15;                       // lane within group == hidden unit
  const int g = tid >> 4;                       // group (batch slot) within block
  const int batch = blockIdx.x * 16 + g;
  const int jo = (j < 5) ? j : 0;               // clamped row for W_lin loads

  // x staging: xs[parity][step-in-chunk][group] as float4 (pad 4th)
  __shared__ float4 xs[2][64][16];
  float4* xsf = &xs[0][0][0];                   // flat: idx = (s&127)*16 + g

  // ---- preload weights into registers, packed by gate-pair, log2e folded
  f32x2 wif[16], wgo[16];                       // {W_i, W_f}[k], {W_g, W_o}[k]
  float wl[16];
#pragma unroll
  for (int k = 0; k < 16; ++k) {
    wif[k] = f32x2{W_hh[(j     ) * 16 + k] * LOG2E,
                   W_hh[(j + 16) * 16 + k] * LOG2E};
    wgo[k] = f32x2{W_hh[(j + 32) * 16 + k] * (2.0f * LOG2E),
                   W_hh[(j + 48) * 16 + k] * LOG2E};
    wl[k]  = W_lin[jo * 16 + k];
  }
  f32x2 xw[3], xwg[3];
#pragma unroll
  for (int i = 0; i < 3; ++i) {
    xw[i]  = f32x2{W_ih[(j     ) * 3 + i] * LOG2E,
                   W_ih[(j + 16) * 3 + i] * LOG2E};
    xwg[i] = f32x2{W_ih[(j + 32) * 3 + i] * (2.0f * LOG2E),
                   W_ih[(j + 48) * 3 + i] * LOG2E};
  }
  const f32x2 bif = f32x2{(b_ih[j     ] + b_hh[j     ]) * LOG2E,
                          (b_ih[j + 16] + b_hh[j + 16]) * LOG2E};
  const f32x2 bgo = f32x2{(b_ih[j + 32] + b_hh[j + 32]) * (2.0f * LOG2E),
                          (b_ih[j + 48] + b_hh[j + 48]) * LOG2E};
  const float bl = b_lin[jo];

  const float* __restrict__ xb = x + (size_t)batch * (TS * 3);
  float* __restrict__ ob = out + (size_t)batch * (TS * 5) + j;
  const bool storer = (j < 5);

  // ---- staging (intra-wave: group g's lanes handle batch g only)
  // lane j of group g owns steps 4j..4j+3 of each chunk (12 floats, 48 B)
  const float* xc0 = xb + j * 12;               // + chunk*192 floats
  float4 q0, q1, q2;                            // 12 staged floats in flight

  // prologue: stage chunk 0, start loads for chunk 1
  q0 = *(const float4*)(xc0 + 0);
  q1 = *(const float4*)(xc0 + 4);
  q2 = *(const float4*)(xc0 + 8);
  {
    const int wb = j * 4 * 16 + g;              // parity 0 base index
    xsf[wb +  0] = float4{q0.x, q0.y, q0.z, 0.f};
    xsf[wb + 16] = float4{q0.w, q1.x, q1.y, 0.f};
    xsf[wb + 32] = float4{q1.z, q1.w, q2.x, 0.f};
    xsf[wb + 48] = float4{q2.y, q2.z, q2.w, 0.f};
  }
  q0 = *(const float4*)(xc0 + 192 + 0);
  q1 = *(const float4*)(xc0 + 192 + 4);
  q2 = *(const float4*)(xc0 + 192 + 8);

  // prefetch x for steps 0 and 1
  float4 xr[2];
  xr[0] = xsf[0 * 16 + g];
  xr[1] = xsf[1 * 16 + g];

  float h = 0.0f, cs = 0.0f;                    // cs = 2*LOG2E * c (scaled cell)

  auto step = [&](int s, int slot) {
    const float4 xt = xr[slot];
    // issue ds_read for step s+2 into the slot just freed
    xr[slot] = xsf[(((s + 2) & 127) << 4) + g];

    // broadcast h_{t-1} across the 16-lane row (DPP, VALU pipe)
    float hbr[16];
    const int hvi = __float_as_int(h);
    BCAST_ALL();

    // gate pre-activations: QUAD pk_fma chains (depth 4 each) + dual oa
    f32x2 aa = bif, ab = f32x2{0.f, 0.f}, ac = f32x2{0.f, 0.f}, ad = f32x2{0.f, 0.f};
    f32x2 ga = bgo, gb = f32x2{0.f, 0.f}, gc = f32x2{0.f, 0.f}, gd = f32x2{0.f, 0.f};
    float oa0 = bl, oa1 = 0.f;
    aa = f32x2{xt.x, xt.x} * xw[0] + aa;
    ab = f32x2{xt.y, xt.y} * xw[1] + ab;
    ac = f32x2{xt.z, xt.z} * xw[2] + ac;
    ga = f32x2{xt.x, xt.x} * xwg[0] + ga;
    gb = f32x2{xt.y, xt.y} * xwg[1] + gb;
    gc = f32x2{xt.z, xt.z} * xwg[2] + gc;
#pragma unroll
    for (int k = 0; k < 16; k += 4) {
      const f32x2 h0 = f32x2{hbr[k],     hbr[k]};
      const f32x2 h1 = f32x2{hbr[k + 1], hbr[k + 1]};
      const f32x2 h2 = f32x2{hbr[k + 2], hbr[k + 2]};
      const f32x2 h3 = f32x2{hbr[k + 3], hbr[k + 3]};
      aa = h0 * wif[k]     + aa;
      ab = h1 * wif[k + 1] + ab;
      ac = h2 * wif[k + 2] + ac;
      ad = h3 * wif[k + 3] + ad;
      ga = h0 * wgo[k]     + ga;
      gb = h1 * wgo[k + 1] + gb;
      gc = h2 * wgo[k + 2] + gc;
      gd = h3 * wgo[k + 3] + gd;
      oa0 = fmaf(hbr[k],     wl[k],     oa0);
      oa1 = fmaf(hbr[k + 1], wl[k + 1], oa1);
      oa0 = fmaf(hbr[k + 2], wl[k + 2], oa0);
      oa1 = fmaf(hbr[k + 3], wl[k + 3], oa1);
    }
    const f32x2 zif = (aa + ab) + (ac + ad);
    const f32x2 zgo = (ga + gb) + (gc + gd);

    // output projection W_lin . h_{t-1} -> out[s-1]
    if (s > 0 && storer) {
      const float oa = oa0 + oa1;
      ob[(s - 1) * 5] = fminf(fmaxf(oa, -10.0f), 10.0f);
    }

    // activations with PAIRED reciprocals:
    //   R = rcp((1+Ea)(1+Eb)); sig_a = (1+Eb)*R; sig_b = (1+Ea)*R  (exact)
    const float Ei = __builtin_amdgcn_exp2f(-zif.x);
    const float Ef = __builtin_amdgcn_exp2f(-zif.y);
    const float Eg = __builtin_amdgcn_exp2f( zgo.x);   // 2*log2e folded in weights
    const float Eo = __builtin_amdgcn_exp2f(-zgo.y);
    const float di = 1.0f + Ei, df = 1.0f + Ef;
    const float dg = 1.0f + Eg, dn = 1.0f + Eo;
    const float Rif = __builtin_amdgcn_rcpf(di * df);
    const float Rgo = __builtin_amdgcn_rcpf(dg * dn);
    const float ig = df * Rif;                  // sigmoid(i)
    const float fg = di * Rif;                  // sigmoid(f)
    const float sg = dn * Rgo;                  // 1/(1+e^{2g})
    const float og = dg * Rgo;                  // sigmoid(o)

    // scaled cell: cs = 2L*c; gg2 = 2L*tanh(g) = 2L - 4L*sg
    const float gg2 = fmaf(-4.0f * LOG2E, sg, 2.0f * LOG2E);
    cs = fmaf(fg, cs, ig * gg2);
    const float tc = fmaf(-2.0f,
        __builtin_amdgcn_rcpf(1.0f + __builtin_amdgcn_exp2f(cs)), 1.0f);
    h = og * tc;
  };

  for (int ch = 0; ch < 8; ++ch) {
    const int base = ch * 64;

    // first half of the chunk
#pragma unroll 2
    for (int u = 0; u < 32; ++u) step(base + u, u & 1);

    // mid-chunk: stage chunk ch+1 (regs loaded ~64 steps ago), start ch+2 loads
    if (ch < 7) {
      const int p = (ch + 1) & 1;
      const int wb = p * 1024 + j * 64 + g;     // [p][4j+i][g] flat
      xsf[wb +  0] = float4{q0.x, q0.y, q0.z, 0.f};
      xsf[wb + 16] = float4{q0.w, q1.x, q1.y, 0.f};
      xsf[wb + 32] = float4{q1.z, q1.w, q2.x, 0.f};
      xsf[wb + 48] = float4{q2.y, q2.z, q2.w, 0.f};
    }
    if (ch < 6) {
      const float* xc = xc0 + (ch + 2) * 192;
      q0 = *(const float4*)(xc + 0);
      q1 = *(const float4*)(xc + 4);
      q2 = *(const float4*)(xc + 8);
    }

    // second half of the chunk
#pragma unroll 2
    for (int u = 32; u < 64; ++u) step(base + u, u & 1);
  }

  // final timestep's output (uses h_{S-1})
  {
    float hbr[16];
    const int hvi = __float_as_int(h);
    BCAST_ALL();
    float oa = bl;
#pragma unroll
    for (int k = 0; k < 16; ++k) oa = fmaf(hbr[k], wl[k], oa);
    if (storer) {
      ob[(TS - 1) * 5] = fminf(fmaxf(oa, -10.0f), 10.0f);
    }
  }
}

extern "C" void kernel_launch(void* const* d_in, const int* in_sizes, int n_in,
                              void* d_out, int out_size, void* d_ws, size_t ws_size,
                              hipStream_t stream) {
  const float* x     = (const float*)d_in[0];
  const float* W_ih  = (const float*)d_in[1];
  const float* W_hh  = (const float*)d_in[2];
  const float* b_ih  = (const float*)d_in[3];
  const float* b_hh  = (const float*)d_in[4];
  const float* W_lin = (const float*)d_in[5];
  const float* b_lin = (const float*)d_in[6];
  float* out = (float*)d_out;

  const int B = in_sizes[0] / (TS * 3);   // 4096
  const int grid = B / 16;                // 16 batch elements per 256-thread block
  lstm_enc_kernel<<<grid, 256, 0, stream>>>(x, W_ih, W_hh, b_ih, b_hh, W_lin, b_lin, out);
}